// Round 13
// baseline (110.128 us; speedup 1.0000x reference)
//
#include <hip/hip_runtime.h>
#include <hip/hip_fp8.h>

// NCE loss: out0 = align + w*uniform, out1 = align, out2 = uniform
// align[n]   = logsig(ref[n]·pos[n]/T)
// uniform[n] = mean_m logsig(-ref[n]·neg[m]/T)
// N=M=8192, D=512, T=0.5, w=1.0
//
// Round 13: MX-fp8 (e4m3, scale=1.0) 32x32x64 MFMA -> 256x256 tile at
// BK=64 with 64KB LDS (2 blocks/CU) and only 1024 blocks (2 generations).
// Same proven round-12 loop (stage-next, read frags, MFMA, syncthreads).
// Swizzle for 64B rows: chunk ^ ((row>>1)&3). align-dot fused into
// cvt_pack (pos read there; combine is tiny).

typedef __attribute__((ext_vector_type(4)))  float f32x4;
typedef __attribute__((ext_vector_type(16))) float f32x16;
typedef __attribute__((ext_vector_type(4)))  int   int4v;
typedef __attribute__((ext_vector_type(8)))  int   int8v;
typedef __attribute__((ext_vector_type(16))) unsigned char uchar16;

constexpr int N_ = 8192;
constexpr int M_ = 8192;
constexpr int D_ = 512;
constexpr float INV_T = 2.0f;
constexpr float NEG_W = 1.0f;
constexpr float LOG2E = 1.4426950408889634f;
constexpr float LN2   = 0.6931471805599453f;
constexpr unsigned SCALE1 = 0x7F7F7F7Fu;  // E8M0 127 -> 2^0 = 1.0

__device__ __forceinline__ float logsig_neg(float s) {
  float t = __builtin_fabsf(s);
  float e = __builtin_amdgcn_exp2f(-t * LOG2E);
  float l = __builtin_amdgcn_logf(1.0f + e) * LN2;
  return fminf(-s, 0.0f) - l;
}

// fp32 -> fp8 e4m3, intra-row swizzle: row = 512B = 8 K-segments x 64B;
// 16B chunk w of a segment stored at w ^ ((row>>1)&3). Also computes
// align-dot (ref.pos) for ref rows (block fully owns 8 rows -> no atomics).
__global__ __launch_bounds__(256) void cvt_pack(
    const float* __restrict__ refp, const float* __restrict__ posp,
    const float* __restrict__ negp, unsigned char* __restrict__ a8,
    unsigned char* __restrict__ b8, float* __restrict__ aligndot) {
  const int b = blockIdx.x;
  const bool isA = (b < 1024);
  const float* src = isA ? refp : negp;
  unsigned char* dst = isA ? a8 : b8;
  const int t   = threadIdx.x;
  const int row = (b & 1023) * 8 + (t >> 5);
  const int ck  = t & 31;  // 16B chunk within row
  const float* sp = src + (size_t)row * 512 + ck * 16;
  f32x4 v[4];
#pragma unroll
  for (int q = 0; q < 4; ++q) v[q] = reinterpret_cast<const f32x4*>(sp)[q];
  uchar16 o;
#pragma unroll
  for (int q = 0; q < 4; ++q)
#pragma unroll
    for (int j = 0; j < 4; ++j) {
      __hip_fp8_e4m3 f(v[q][j]);
      o[q * 4 + j] = f.__x;
    }
  if (isA) {
    const float* pp = posp + (size_t)row * 512 + ck * 16;
    float dot = 0.0f;
#pragma unroll
    for (int q = 0; q < 4; ++q) {
      f32x4 pv = reinterpret_cast<const f32x4*>(pp)[q];
#pragma unroll
      for (int j = 0; j < 4; ++j) dot = __builtin_fmaf(v[q][j], pv[j], dot);
    }
    dot += __shfl_xor(dot, 1);
    dot += __shfl_xor(dot, 2);
    dot += __shfl_xor(dot, 4);
    dot += __shfl_xor(dot, 8);
    dot += __shfl_xor(dot, 16);
    if (ck == 0) aligndot[row] = dot;
  }
  const unsigned seg = (unsigned)ck >> 2;
  const unsigned w   = (unsigned)ck & 3;
  const unsigned sw  = ((unsigned)row >> 1) & 3;
  *reinterpret_cast<uchar16*>(dst + (size_t)row * 512 + seg * 64 +
                              ((w ^ sw) << 4)) = o;
}

__global__ __launch_bounds__(512, 2) void nce_gemm(
    const unsigned char* __restrict__ A,  // ref fp8, pre-swizzled rows
    const unsigned char* __restrict__ B,  // neg fp8, pre-swizzled rows
    float* __restrict__ rowsum) {         // (N,) fp32, pre-zeroed
  // 2 bufs x (A 256x64B + B 256x64B) = 64 KiB -> 2 blocks/CU
  __shared__ __align__(16) char As[2][16384];
  __shared__ __align__(16) char Bs[2][16384];

  const int tid  = threadIdx.x;
  const int lane = tid & 63;
  const int wid  = tid >> 6;   // 0..7
  const int wr   = wid >> 2;   // 0..1 (A half: 128 rows)
  const int wc   = wid & 3;    // 0..3 (B quarter: 64 cols)
  const int l31  = lane & 31;
  const int kh   = lane >> 5;  // K-half selector (32B of the 64B row)

  // XCD swizzle: 1024 blocks, 8 XCDs, 4 row-bands/XCD, col-major in band
  const int bid  = blockIdx.x;
  const int x    = bid & 7;
  const int t    = bid >> 3;   // 0..127
  const int brow = (x * 4 + (t & 3)) * 256;
  const int bcol = (t >> 2) * 256;

  // staging per-lane source (4 threads cover one 64B segment)
  const char* gA = reinterpret_cast<const char*>(A) +
                   (size_t)(brow + (tid >> 2)) * 512 + (tid & 3) * 16;
  const char* gB = reinterpret_cast<const char*>(B) +
                   (size_t)(bcol + (tid >> 2)) * 512 + (tid & 3) * 16;

  f32x16 acc[4][2];
#pragma unroll
  for (int i = 0; i < 4; ++i)
#pragma unroll
    for (int j = 0; j < 2; ++j) acc[i][j] = (f32x16)0.0f;

  int8v aF[4], bF[2];

  // stage K-tile g (A 16KB + B 16KB), 4 glds per thread
#define STAGE(g, buf)                                                         \
  {                                                                           \
    _Pragma("unroll") for (int j = 0; j < 2; ++j) {                           \
      __builtin_amdgcn_global_load_lds(                                       \
          (const __attribute__((address_space(1))) unsigned int*)(            \
              gA + (size_t)j * 65536 + (size_t)(g) * 64),                     \
          (__attribute__((address_space(3))) unsigned int*)(                  \
              &As[buf][j * 8192 + tid * 16]),                                 \
          16, 0, 0);                                                          \
      __builtin_amdgcn_global_load_lds(                                       \
          (const __attribute__((address_space(1))) unsigned int*)(            \
              gB + (size_t)j * 65536 + (size_t)(g) * 64),                     \
          (__attribute__((address_space(3))) unsigned int*)(                  \
              &Bs[buf][j * 8192 + tid * 16]),                                 \
          16, 0, 0);                                                          \
    }                                                                         \
  }

  // fragment: lane reads 32B of row = its K-half, via 2 swizzled b128
#define FRAG(base, row, DSTV)                                                 \
  {                                                                           \
    const int sw_ = (((row) >> 1) & 3);                                       \
    const int c0_ = (((2 * kh) ^ sw_) << 4);                                  \
    const char* p_ = (base) + (row) * 64;                                     \
    int4v lo_ = *reinterpret_cast<const int4v*>(p_ + c0_);                    \
    int4v hi_ = *reinterpret_cast<const int4v*>(p_ + (c0_ ^ 16));             \
    DSTV = __builtin_shufflevector(lo_, hi_, 0, 1, 2, 3, 4, 5, 6, 7);         \
  }

  // ---- prologue ----
  STAGE(0, 0);
  __syncthreads();

  // ---- main loop: 8 K-tiles of 64 ----
#pragma unroll
  for (int kt = 0; kt < 8; ++kt) {
    const int cur = kt & 1;
    if (kt + 1 < 8) STAGE(kt + 1, cur ^ 1);  // prefetch overlaps compute

#pragma unroll
    for (int mf = 0; mf < 4; ++mf)
      FRAG(As[cur], wr * 128 + mf * 32 + l31, aF[mf]);
#pragma unroll
    for (int nf = 0; nf < 2; ++nf)
      FRAG(Bs[cur], wc * 64 + nf * 32 + l31, bF[nf]);

    __builtin_amdgcn_s_setprio(1);
#pragma unroll
    for (int mf = 0; mf < 4; ++mf)
#pragma unroll
      for (int nf = 0; nf < 2; ++nf)
        acc[mf][nf] = __builtin_amdgcn_mfma_scale_f32_32x32x64_f8f6f4(
            aF[mf], bF[nf], acc[mf][nf], 0, 0, 0, SCALE1, 0, SCALE1);
    __builtin_amdgcn_s_setprio(0);

    __syncthreads();  // staged tile ready; LDS reads done
  }
#undef STAGE
#undef FRAG

  // ---- epilogue: uni = logsig(-s*INV_T); reduce over 64 cols/wave ----
  // 32x32 C layout: col = lane&31, row = (rg&3) + 8*(rg>>2) + 4*(lane>>5)
#pragma unroll
  for (int mf = 0; mf < 4; ++mf) {
    float red[16];
#pragma unroll
    for (int rg = 0; rg < 16; ++rg) {
      float v = logsig_neg(acc[mf][0][rg] * INV_T) +
                logsig_neg(acc[mf][1][rg] * INV_T);
      v += __shfl_xor(v, 1);
      v += __shfl_xor(v, 2);
      v += __shfl_xor(v, 4);
      v += __shfl_xor(v, 8);
      v += __shfl_xor(v, 16);
      red[rg] = v;
    }
    if (l31 == 0) {
#pragma unroll
      for (int rg = 0; rg < 16; ++rg) {
        const int row =
            brow + wr * 128 + mf * 32 + (rg & 3) + 8 * (rg >> 2) + 4 * kh;
        atomicAdd(&rowsum[row], red[rg]);
      }
    }
  }
}

__global__ __launch_bounds__(256) void nce_combine(
    const float* __restrict__ aligndot, const float* __restrict__ rowsum,
    float* __restrict__ out) {
  const int n = blockIdx.x * 256 + threadIdx.x;
  float z = aligndot[n] * INV_T;
  float align   = logsig_neg(-z);
  float uniform = rowsum[n] * (1.0f / (float)M_);
  out[n]          = align + NEG_W * uniform;
  out[N_ + n]     = align;
  out[2 * N_ + n] = uniform;
}

extern "C" void kernel_launch(void* const* d_in, const int* in_sizes, int n_in,
                              void* d_out, int out_size, void* d_ws,
                              size_t ws_size, hipStream_t stream) {
  const float* ref = (const float*)d_in[0];
  const float* pos = (const float*)d_in[1];
  const float* neg = (const float*)d_in[2];
  float* out = (float*)d_out;

  float* rowsum   = (float*)d_ws;                      // 32 KB
  float* aligndot = (float*)((char*)d_ws + 32768);     // 32 KB
  unsigned char* a8 = (unsigned char*)d_ws + 65536;    // 4 MB
  unsigned char* b8 = a8 + (size_t)N_ * D_;            // 4 MB

  hipMemsetAsync(rowsum, 0, N_ * sizeof(float), stream);
  cvt_pack<<<2048, 256, 0, stream>>>(ref, pos, neg, a8, b8, aligndot);
  nce_gemm<<<1024, 512, 0, stream>>>(a8, b8, rowsum);
  nce_combine<<<N_ / 256, 256, 0, stream>>>(aligndot, rowsum, out);
}